// Round 13
// baseline (242.193 us; speedup 1.0000x reference)
//
#include <hip/hip_runtime.h>
#include <hip/hip_bf16.h>

#define N_GRAPHS 200
#define NPG      500
#define NPGP     512                   // padded nodes per graph (MFMA tiles)
#define N_NODES_ 100000
#define N_EDGES_ 1600000
#define DIN      64
#define DG       128
#define SEQ      20
#define HL       128
#define G4       512
#define BWIN     (N_GRAPHS - SEQ + 1)  // 181
#define NPART    256
#define EPB      (N_EDGES_/NPART)      // 6250
#define SLOTS    80                    // per-(graph,block) cell capacity (8.7 sigma)
#define GCAP     (NPART*SLOTS)         // 20480 per-graph segment
#define ECAP     9500                  // per-graph edge cap in LDS (16.8 sigma)

typedef __attribute__((ext_vector_type(8))) short short8;
typedef __attribute__((ext_vector_type(4))) float float4v;
typedef __attribute__((ext_vector_type(2))) _Float16 half2v;

__device__ __forceinline__ float sigmoidf_(float v){ return 1.0f/(1.0f+expf(-v)); }

// fp32 -> bf16 round-to-nearest-even
__device__ __forceinline__ unsigned short f2bf(float f) {
  unsigned int u = __float_as_uint(f);
  u += 0x7fffu + ((u >> 16) & 1u);
  return (unsigned short)(u >> 16);
}

__device__ __forceinline__ float h2dot(half2v a, half2v b, float c) {
#if __has_builtin(__builtin_amdgcn_fdot2)
  return __builtin_amdgcn_fdot2(a, b, c, false);
#else
  return c + (float)a.x*(float)b.x + (float)a.y*(float)b.y;
#endif
}

// K1: partition into FIXED per-(graph,block) cells. No global atomics, no
// memset needed (cnt2 fully written). LDS-buffered, coalesced cell flush.
__global__ __launch_bounds__(256) void k_part(const int* __restrict__ src,
                                              const int* __restrict__ dst,
                                              int* __restrict__ cnt2,
                                              int* __restrict__ part) {
  __shared__ int cnt[N_GRAPHS];
  __shared__ int buf[N_GRAPHS][SLOTS];   // 64 KB
  int b = blockIdx.x, t = threadIdx.x;
  for (int g = t; g < N_GRAPHS; g += 256) cnt[g] = 0;
  __syncthreads();
  int e0 = b*EPB;
  for (int i = t; i < EPB; i += 256) {
    int s = src[e0+i], d = dst[e0+i];
    int g = s / NPG;
    int sl = s - g*NPG, dl = d - g*NPG;
    int pos = atomicAdd(&cnt[g], 1);
    if (pos < SLOTS) buf[g][pos] = (sl << 9) | dl;
  }
  __syncthreads();
  int w = t >> 6, lane = t & 63;
  for (int g = w; g < N_GRAPHS; g += 4) {
    int n = min(cnt[g], SLOTS);
    int* dp = part + (size_t)g*GCAP + b*SLOTS;
    for (int j = lane; j < n; j += 64) dp[j] = buf[g][j];
  }
  for (int g = t; g < N_GRAPHS; g += 256) cnt2[g*NPART + b] = min(cnt[g], SLOTS);
}

// K2: per-graph mega-kernel. Phases: A) compact cells + histogram + scans +
// counting sort (sorted stays in LDS); B) stage bf16 x*so into LDS with XOR
// bank swizzle; C) aggregation with LDS gathers (round-3's mega failed because
// gathers hit GLOBAL at 1 block/CU; LDS gathers are the fix); D) MFMA GEMM +
// ReLU + mean-pool + fused w_ih projection. ~151 KB LDS, 1 block/CU.
__global__ __launch_bounds__(512) void k_graph(
    const int* __restrict__ cnt2, const int* __restrict__ part,
    const float* __restrict__ x,
    const float* __restrict__ w_gcn, const float* __restrict__ b_gcn,
    const float* __restrict__ w_ih, const float* __restrict__ b_ih,
    float* __restrict__ proj) {
  __shared__ __align__(16) char smem[154624];
  __shared__ int EtotS;
  // persistent regions
  unsigned short* hpreLds   = (unsigned short*)(smem + 64000);   // 65536 B
  unsigned short* sortedLds = (unsigned short*)(smem + 129536);  // 19000 B
  float* soS  = (float*)(smem + 148536);                         // 2000 B
  int*   ndegL= (int*)(smem + 150536);                           // 2000 B
  int*   nendL= (int*)(smem + 152536);                           // 2000 B
  // phase-A scratch (aliases xLds region [0,64000))
  int* cntS  = (int*)(smem);
  int* offC  = (int*)(smem + 1024);
  int* indeg = (int*)(smem + 2048);
  int* outdeg= (int*)(smem + 4048);
  int* offN  = (int*)(smem + 6048);
  int* sA    = (int*)(smem + 8048);
  int* sB    = (int*)(smem + 10096);
  int* edges = (int*)(smem + 12144);   // 9500 ints -> ends 50144

  int g = blockIdx.x, t = threadIdx.x;

  // ---- A1: scan cell counts ----
  int cv = 0;
  if (t < NPART) { cv = cnt2[g*NPART + t]; cntS[t] = cv; }
  sA[t] = (t < NPART) ? cv : 0;
  __syncthreads();
  int* cur = sA; int* nxt = sB;
  for (int o = 1; o < 512; o <<= 1) {
    nxt[t] = cur[t] + ((t >= o) ? cur[t-o] : 0);
    __syncthreads();
    int* tmp = cur; cur = nxt; nxt = tmp;
  }
  if (t < NPART) offC[t] = cur[t] - cv;
  if (t == NPART-1) EtotS = cur[t];
  if (t < NPG) { indeg[t] = 0; outdeg[t] = 0; }
  __syncthreads();
  int E = min(EtotS, ECAP);

  // ---- A2: compact cells into LDS + histogram ----
  const int* pg = part + (size_t)g*GCAP;
  for (int idx = t; idx < GCAP; idx += 512) {
    int cc = idx / SLOTS, j = idx - cc*SLOTS;
    if (j < cntS[cc]) {
      int p = pg[idx];
      edges[offC[cc] + j] = p;
      atomicAdd(&indeg[p & 511], 1);
      atomicAdd(&outdeg[p >> 9], 1);
    }
  }
  __syncthreads();

  // ---- A3: scan indeg -> offN ----
  int v = (t < NPG) ? indeg[t] : 0;
  sA[t] = v; __syncthreads();
  cur = sA; nxt = sB;
  for (int o = 1; o < 512; o <<= 1) {
    nxt[t] = cur[t] + ((t >= o) ? cur[t-o] : 0);
    __syncthreads();
    int* tmp = cur; cur = nxt; nxt = tmp;
  }
  if (t < NPG) {
    offN[t] = cur[t] - v;
    soS[t] = rsqrtf((float)max(outdeg[t], 1));
    ndegL[t] = indeg[t];
  }
  __syncthreads();

  // ---- A4: counting-sort scatter into LDS ----
  for (int i = t; i < E; i += 512) {
    int p = edges[i];
    int pos = atomicAdd(&offN[p & 511], 1);
    if (pos < ECAP) sortedLds[pos] = (unsigned short)(p >> 9);
  }
  __syncthreads();
  if (t < NPG) nendL[t] = offN[t];     // inclusive end
  __syncthreads();

  // ---- B: stage xLds = bf16(x * so), XOR-swizzled int4 columns ----
  const float4* xg = ((const float4*)x) + (size_t)g*8000;   // 500*16
  ushort4* xw = (ushort4*)smem;
  for (int i = t; i < 8000; i += 512) {
    int row = i >> 4, col = i & 15;
    float s = soS[row];
    float4 vv = xg[i];
    ushort4 u;
    u.x = f2bf(vv.x*s); u.y = f2bf(vv.y*s); u.z = f2bf(vv.z*s); u.w = f2bf(vv.w*s);
    int cI = col >> 1;
    int sw = (((cI + row) & 7) << 1) | (col & 1);
    xw[(row << 4) + sw] = u;
  }
  __syncthreads();

  // ---- C: aggregation, LDS gathers; wave per node slot, 8 lanes/edge ----
  int w8 = t >> 6, lane = t & 63, g8 = lane >> 3, fl = lane & 7;
  const int4* xI4 = (const int4*)smem;
  int4* hpI4 = (int4*)(smem + 64000);
  for (int nl = w8; nl < NPGP; nl += 8) {
    if (nl >= NPG) {
      if (g8 == 0) hpI4[nl*8 + fl] = make_int4(0,0,0,0);
      continue;
    }
    int end = nendL[nl], deg = ndegL[nl], start = end - deg;
    float aHi[4] = {0.f,0.f,0.f,0.f};
    float aLo[4] = {0.f,0.f,0.f,0.f};
    for (int i = start + (g8 << 1); i < end; i += 16) {
      int s0 = (int)sortedLds[i];
      int4 vv = xI4[(s0 << 3) + ((fl + s0) & 7)];
      aHi[0] += __uint_as_float((unsigned)vv.x & 0xffff0000u);
      aLo[0] += __uint_as_float((unsigned)vv.x << 16);
      aHi[1] += __uint_as_float((unsigned)vv.y & 0xffff0000u);
      aLo[1] += __uint_as_float((unsigned)vv.y << 16);
      aHi[2] += __uint_as_float((unsigned)vv.z & 0xffff0000u);
      aLo[2] += __uint_as_float((unsigned)vv.z << 16);
      aHi[3] += __uint_as_float((unsigned)vv.w & 0xffff0000u);
      aLo[3] += __uint_as_float((unsigned)vv.w << 16);
      if (i + 1 < end) {
        int s1 = (int)sortedLds[i+1];
        int4 ww = xI4[(s1 << 3) + ((fl + s1) & 7)];
        aHi[0] += __uint_as_float((unsigned)ww.x & 0xffff0000u);
        aLo[0] += __uint_as_float((unsigned)ww.x << 16);
        aHi[1] += __uint_as_float((unsigned)ww.y & 0xffff0000u);
        aLo[1] += __uint_as_float((unsigned)ww.y << 16);
        aHi[2] += __uint_as_float((unsigned)ww.z & 0xffff0000u);
        aLo[2] += __uint_as_float((unsigned)ww.z << 16);
        aHi[3] += __uint_as_float((unsigned)ww.w & 0xffff0000u);
        aLo[3] += __uint_as_float((unsigned)ww.w << 16);
      }
    }
    #pragma unroll
    for (int m = 8; m < 64; m <<= 1) {
      #pragma unroll
      for (int d = 0; d < 4; ++d) {
        aHi[d] += __shfl_xor(aHi[d], m);
        aLo[d] += __shfl_xor(aLo[d], m);
      }
    }
    if (g8 == 0) {
      float sn = rsqrtf((float)max(deg, 1));
      int4 outv;
      outv.x = (int)(((unsigned)f2bf(aLo[0]*sn)) | ((unsigned)f2bf(aHi[0]*sn) << 16));
      outv.y = (int)(((unsigned)f2bf(aLo[1]*sn)) | ((unsigned)f2bf(aHi[1]*sn) << 16));
      outv.z = (int)(((unsigned)f2bf(aLo[2]*sn)) | ((unsigned)f2bf(aHi[2]*sn) << 16));
      outv.w = (int)(((unsigned)f2bf(aLo[3]*sn)) | ((unsigned)f2bf(aHi[3]*sn) << 16));
      hpI4[nl*8 + fl] = outv;
    }
  }
  __syncthreads();

  // ---- D: MFMA GEMM + ReLU + mean pool + fused projection ----
  unsigned short* wLds = (unsigned short*)smem;         // 16384 B (aliases xLds, dead)
  float* pS  = (float*)(smem + 16384);                  // 8*128*4 = 4096
  float* hgS = (float*)(smem + 16384 + 4096);           // 512
  for (int idx = t; idx < 16*64; idx += 512) {
    int f = idx >> 6, l = idx & 63;
    int h = f & 1, nt = f >> 1;
    int kbase = h*32 + (l >> 4)*8;
    int n = nt*16 + (l & 15);
    #pragma unroll
    for (int j = 0; j < 8; ++j)
      wLds[idx*8 + j] = f2bf(w_gcn[(kbase + j)*DG + n]);
  }
  __syncthreads();
  int quad = lane >> 4, l15 = lane & 15;
  float bcol[8];
  #pragma unroll
  for (int nt = 0; nt < 8; ++nt) bcol[nt] = b_gcn[nt*16 + l15];
  float psum[8] = {0.f,0.f,0.f,0.f,0.f,0.f,0.f,0.f};
  const unsigned short* hb = (const unsigned short*)(smem + 64000);
  for (int i = 0; i < 4; ++i) {
    int rt = w8 + 8*i;
    int row0 = rt*16;
    const short8* aptr = (const short8*)(hb + (size_t)(row0 + l15)*64 + quad*8);
    short8 a0 = aptr[0];
    short8 a1 = aptr[4];
    #pragma unroll
    for (int nt = 0; nt < 8; ++nt) {
      short8 b0 = *((const short8*)&wLds[((nt*2+0)*64 + lane)*8]);
      short8 b1 = *((const short8*)&wLds[((nt*2+1)*64 + lane)*8]);
      float4v acc = {0.f, 0.f, 0.f, 0.f};
      acc = __builtin_amdgcn_mfma_f32_16x16x32_bf16(a0, b0, acc, 0, 0, 0);
      acc = __builtin_amdgcn_mfma_f32_16x16x32_bf16(a1, b1, acc, 0, 0, 0);
      #pragma unroll
      for (int r = 0; r < 4; ++r) {
        int node = row0 + quad*4 + r;
        float vvv = acc[r] + bcol[nt];
        psum[nt] += (node < NPG) ? fmaxf(vvv, 0.f) : 0.f;
      }
    }
  }
  #pragma unroll
  for (int nt = 0; nt < 8; ++nt) {
    float vv = psum[nt];
    vv += __shfl_xor(vv, 16);
    vv += __shfl_xor(vv, 32);
    if (lane < 16) pS[w8*DG + nt*16 + lane] = vv;
  }
  __syncthreads();
  if (t < DG) {
    float s = 0.f;
    #pragma unroll
    for (int ww = 0; ww < 8; ++ww) s += pS[ww*DG + t];
    hgS[t] = s * (1.0f/NPG);
  }
  __syncthreads();
  {
    int r = t;                                  // 512 threads == G4 rows
    const float4* wr = (const float4*)(w_ih + (size_t)r*HL);
    const float4* hv = (const float4*)hgS;
    float acc = b_ih[r];
    #pragma unroll
    for (int k4 = 0; k4 < 32; ++k4) {
      float4 w4 = wr[k4]; float4 h4 = hv[k4];
      acc += w4.x*h4.x + w4.y*h4.y + w4.z*h4.z + w4.w*h4.w;
    }
    proj[(size_t)g*G4 + r] = acc;
  }
}

// K3: LSTM — w_hh fp16 CU-resident in LDS; h packed fp16; fp32 accumulation.
__global__ __launch_bounds__(512) void k_lstm(const float* __restrict__ proj,
    const float* __restrict__ w_hh, const float* __restrict__ b_hh,
    const float* __restrict__ w_fc, const float* __restrict__ b_fc,
    float* __restrict__ out) {
  __shared__ int4 wL[16*512];        // 128 KB: [k4][r] = 8 fp16 of w_hh[r][k4*8..]
  __shared__ float gS[G4];
  __shared__ __align__(16) int4 hPi[16];  // 128 fp16 packed h state
  int b = blockIdx.x, t = threadIdx.x;
  for (int i = t; i < 16*512; i += 512) {
    int k4 = i >> 9, r = i & 511;
    const float4* wp = (const float4*)(w_hh + (size_t)r*HL + k4*8);
    float4 w0 = wp[0], w1 = wp[1];
    half2v p0 = {(_Float16)w0.x, (_Float16)w0.y};
    half2v p1 = {(_Float16)w0.z, (_Float16)w0.w};
    half2v p2 = {(_Float16)w1.x, (_Float16)w1.y};
    half2v p3 = {(_Float16)w1.z, (_Float16)w1.w};
    int4 pk;
    pk.x = __builtin_bit_cast(int, p0); pk.y = __builtin_bit_cast(int, p1);
    pk.z = __builtin_bit_cast(int, p2); pk.w = __builtin_bit_cast(int, p3);
    wL[i] = pk;
  }
  if (t < 16) hPi[t] = make_int4(0,0,0,0);
  float bh = b_hh[t];
  float c0 = 0.f, c1 = 0.f;
  __syncthreads();
  for (int l = 0; l < SEQ; ++l) {
    float acc = proj[(size_t)(b+l)*G4 + t] + bh;
    #pragma unroll
    for (int k4 = 0; k4 < 16; ++k4) {
      int4 wv = wL[(k4 << 9) + t];
      int4 hv = hPi[k4];
      acc = h2dot(__builtin_bit_cast(half2v, wv.x), __builtin_bit_cast(half2v, hv.x), acc);
      acc = h2dot(__builtin_bit_cast(half2v, wv.y), __builtin_bit_cast(half2v, hv.y), acc);
      acc = h2dot(__builtin_bit_cast(half2v, wv.z), __builtin_bit_cast(half2v, hv.z), acc);
      acc = h2dot(__builtin_bit_cast(half2v, wv.w), __builtin_bit_cast(half2v, hv.w), acc);
    }
    gS[t] = acc;
    __syncthreads();
    if (t < 64) {
      int j0 = 2*t, j1 = 2*t + 1;
      float i0 = sigmoidf_(gS[j0]),      i1 = sigmoidf_(gS[j1]);
      float f0 = sigmoidf_(gS[HL+j0]),   f1 = sigmoidf_(gS[HL+j1]);
      float g0 = tanhf(gS[2*HL+j0]),     g1 = tanhf(gS[2*HL+j1]);
      float o0 = sigmoidf_(gS[3*HL+j0]), o1 = sigmoidf_(gS[3*HL+j1]);
      c0 = f0*c0 + i0*g0;
      c1 = f1*c1 + i1*g1;
      float h0 = o0 * tanhf(c0);
      float h1 = o1 * tanhf(c1);
      half2v hp = {(_Float16)h0, (_Float16)h1};
      ((int*)hPi)[t] = __builtin_bit_cast(int, hp);
      if (l == SEQ-1) {
        float s = h0*w_fc[j0] + h1*w_fc[j1];
        #pragma unroll
        for (int off = 32; off > 0; off >>= 1) s += __shfl_down(s, off);
        if (t == 0) out[b] = s + b_fc[0];
      }
    }
    __syncthreads();
  }
}

extern "C" void kernel_launch(void* const* d_in, const int* in_sizes, int n_in,
                              void* d_out, int out_size, void* d_ws, size_t ws_size,
                              hipStream_t stream) {
  const float* x     = (const float*)d_in[0];
  const int*   src   = (const int*)d_in[1];
  const int*   dst   = (const int*)d_in[2];
  const float* w_gcn = (const float*)d_in[4];
  const float* b_gcn = (const float*)d_in[5];
  const float* w_ih  = (const float*)d_in[6];
  const float* w_hh  = (const float*)d_in[7];
  const float* b_ih  = (const float*)d_in[8];
  const float* b_hh  = (const float*)d_in[9];
  const float* w_fc  = (const float*)d_in[10];
  const float* b_fc  = (const float*)d_in[11];
  float* out = (float*)d_out;

  char* ws = (char*)d_ws;
  size_t off = 0;
  auto alloc = [&](size_t bytes) -> void* {
    void* p = ws + off; off += (bytes + 255) & ~(size_t)255; return p;
  };
  int* cnt2    = (int*)alloc((size_t)N_GRAPHS*NPART*4);
  int* part    = (int*)alloc((size_t)N_GRAPHS*GCAP*4);
  float* proj  = (float*)alloc((size_t)N_GRAPHS*G4*4);
  (void)ws_size; (void)in_sizes; (void)n_in; (void)out_size;

  k_part<<<NPART, 256, 0, stream>>>(src, dst, cnt2, part);
  k_graph<<<N_GRAPHS, 512, 0, stream>>>(cnt2, part, x, w_gcn, b_gcn, w_ih, b_ih, proj);
  k_lstm<<<BWIN, 512, 0, stream>>>(proj, w_hh, b_hh, w_fc, b_fc, out);
}

// Round 14
// 236.539 us; speedup vs baseline: 1.0239x; 1.0239x over previous
//
#include <hip/hip_runtime.h>
#include <hip/hip_bf16.h>

#define N_GRAPHS 200
#define NPG      500
#define NPGP     512                   // padded nodes per graph (MFMA tiles)
#define N_NODES_ 100000
#define N_EDGES_ 1600000
#define DIN      64
#define DG       128
#define SEQ      20
#define HL       128
#define G4       512
#define BWIN     (N_GRAPHS - SEQ + 1)  // 181
#define NPART    256
#define EPB      (N_EDGES_/NPART)      // 6250
#define SLOTS    80                    // per-(graph,block) cell capacity (8.7 sigma)
#define GCAP     (NPART*SLOTS)         // 20480 per-graph cell segment
#define ECAP     9500                  // per-graph edge cap (16.8 sigma)
#define SCAP     9600                  // sorted_all per-graph stride

typedef __attribute__((ext_vector_type(8))) short short8;
typedef __attribute__((ext_vector_type(4))) float float4v;
typedef __attribute__((ext_vector_type(2))) _Float16 half2v;

__device__ __forceinline__ float sigmoidf_(float v){ return 1.0f/(1.0f+expf(-v)); }

// fp32 -> bf16 round-to-nearest-even
__device__ __forceinline__ unsigned short f2bf(float f) {
  unsigned int u = __float_as_uint(f);
  u += 0x7fffu + ((u >> 16) & 1u);
  return (unsigned short)(u >> 16);
}

__device__ __forceinline__ float h2dot(half2v a, half2v b, float c) {
#if __has_builtin(__builtin_amdgcn_fdot2)
  return __builtin_amdgcn_fdot2(a, b, c, false);
#else
  return c + (float)a.x*(float)b.x + (float)a.y*(float)b.y;
#endif
}

// K1: partition into FIXED per-(graph,block) cells. No global atomics, no
// memset (cnt2 fully written). LDS-buffered, coalesced cell flush.
__global__ __launch_bounds__(256) void k_part(const int* __restrict__ src,
                                              const int* __restrict__ dst,
                                              int* __restrict__ cnt2,
                                              int* __restrict__ part) {
  __shared__ int cnt[N_GRAPHS];
  __shared__ int buf[N_GRAPHS][SLOTS];   // 64 KB
  int b = blockIdx.x, t = threadIdx.x;
  for (int g = t; g < N_GRAPHS; g += 256) cnt[g] = 0;
  __syncthreads();
  int e0 = b*EPB;
  for (int i = t; i < EPB; i += 256) {
    int s = src[e0+i], d = dst[e0+i];
    int g = s / NPG;
    int sl = s - g*NPG, dl = d - g*NPG;
    int pos = atomicAdd(&cnt[g], 1);
    if (pos < SLOTS) buf[g][pos] = (sl << 9) | dl;
  }
  __syncthreads();
  int w = t >> 6, lane = t & 63;
  for (int g = w; g < N_GRAPHS; g += 4) {
    int n = min(cnt[g], SLOTS);
    int* dp = part + (size_t)g*GCAP + b*SLOTS;
    for (int j = lane; j < n; j += 64) dp[j] = buf[g][j];
  }
  for (int g = t; g < N_GRAPHS; g += 256) cnt2[g*NPART + b] = min(cnt[g], SLOTS);
}

// K2: per-graph — compact cells to LDS, histogram, scans, counting sort to
// GLOBAL sorted_all (k_agg stays high-occupancy), node metadata, fused xprep.
__global__ __launch_bounds__(512) void k_sort(const int* __restrict__ cnt2,
    const int* __restrict__ part, const float* __restrict__ x,
    unsigned short* __restrict__ sorted_all,
    int* __restrict__ e_end, int* __restrict__ e_deg,
    ushort4* __restrict__ xsb) {
  __shared__ int edges[ECAP];            // 38000 B
  __shared__ int cntS[NPART], offC[NPART];
  __shared__ int indeg[NPG], outdeg[NPG], offN[NPG];
  __shared__ float soS[NPG];
  __shared__ int sA[512], sB[512];
  __shared__ int EtotS;
  int g = blockIdx.x, t = threadIdx.x;

  int cv = 0;
  if (t < NPART) { cv = cnt2[g*NPART + t]; cntS[t] = cv; }
  sA[t] = (t < NPART) ? cv : 0;
  if (t < NPG) { indeg[t] = 0; outdeg[t] = 0; }
  __syncthreads();
  int* cur = sA; int* nxt = sB;
  for (int o = 1; o < 512; o <<= 1) {
    nxt[t] = cur[t] + ((t >= o) ? cur[t-o] : 0);
    __syncthreads();
    int* tmp = cur; cur = nxt; nxt = tmp;
  }
  if (t < NPART) offC[t] = cur[t] - cv;
  if (t == NPART-1) EtotS = cur[t];
  __syncthreads();

  // compact cells into LDS + histogram
  const int* pg = part + (size_t)g*GCAP;
  for (int idx = t; idx < GCAP; idx += 512) {
    int c = idx / SLOTS, j = idx - c*SLOTS;
    if (j < cntS[c]) {
      int e = offC[c] + j;
      if (e < ECAP) {
        int p = pg[idx];
        edges[e] = p;
        atomicAdd(&indeg[p & 511], 1);
        atomicAdd(&outdeg[p >> 9], 1);
      }
    }
  }
  __syncthreads();

  // scan indeg -> offN (exclusive)
  int v = (t < NPG) ? indeg[t] : 0;
  sA[t] = v; __syncthreads();
  cur = sA; nxt = sB;
  for (int o = 1; o < 512; o <<= 1) {
    nxt[t] = cur[t] + ((t >= o) ? cur[t-o] : 0);
    __syncthreads();
    int* tmp = cur; cur = nxt; nxt = tmp;
  }
  if (t < NPG) {
    offN[t] = cur[t] - v;
    soS[t] = rsqrtf((float)max(outdeg[t], 1));
    e_deg[g*NPG + t] = indeg[t];
  }
  __syncthreads();

  // counting-sort scatter to global sorted_all
  int E = min(EtotS, ECAP);
  for (int i = t; i < E; i += 512) {
    int p = edges[i];
    int pos = atomicAdd(&offN[p & 511], 1);
    sorted_all[g*SCAP + pos] = (unsigned short)(p >> 9);
  }
  __syncthreads();
  if (t < NPG) e_end[g*NPG + t] = g*SCAP + offN[t];   // inclusive end
  __syncthreads();

  // fused xprep: xsb[n][k] = bf16(x[n][k] * so[n])
  const float4* xg = ((const float4*)x) + (size_t)g*8000;   // 500*16
  ushort4* og = xsb + (size_t)g*8000;
  for (int i = t; i < 8000; i += 512) {
    float4 vv = xg[i];
    float s = soS[i >> 4];
    ushort4 u;
    u.x = f2bf(vv.x*s); u.y = f2bf(vv.y*s); u.z = f2bf(vv.z*s); u.w = f2bf(vv.w*s);
    og[i] = u;
  }
}

// K3: aggregation — wave per node slot; 8 lanes per edge (int4 = 8 bf16),
// 4-edge unroll per group. Packed-bf16 accumulate (exact). XCD swizzle.
__global__ __launch_bounds__(256) void k_agg(const int4* __restrict__ xsb,
    const int* __restrict__ e_end, const int* __restrict__ e_deg,
    const unsigned short* __restrict__ sorted_all,
    unsigned short* __restrict__ hpreb) {
  int b = blockIdx.x;
  int xcd = b & 7;
  int i_ = b >> 3;                       // 0..3199
  int g = (i_ >> 7)*8 + xcd;             // g % 8 == xcd
  int t = threadIdx.x;
  int nl = ((i_ & 127) << 2) + (t >> 6); // node slot 0..511 within graph
  int npad = g*NPGP + nl;
  int lane = t & 63, g8 = lane >> 3, fl = lane & 7;
  if (nl >= NPG) {                       // pad rows -> zeros
    if (g8 == 0) {
      int4 z = make_int4(0,0,0,0);
      ((int4*)hpreb)[(size_t)npad*8 + fl] = z;
    }
    return;
  }
  int n = g*NPG + nl;
  int end = e_end[n], deg = e_deg[n], start = end - deg;
  const int4* xg = xsb + (size_t)g*4000;      // 500 rows * 8 int4
  float aHi[4] = {0.f,0.f,0.f,0.f};
  float aLo[4] = {0.f,0.f,0.f,0.f};
  for (int i = start + (g8 << 2); i < end; i += 32) {
    int sj[4];
    #pragma unroll
    for (int j = 0; j < 4; ++j) sj[j] = (i + j < end) ? (int)sorted_all[i+j] : -1;
    #pragma unroll
    for (int j = 0; j < 4; ++j) if (sj[j] >= 0) {
      int4 v = xg[sj[j]*8 + fl];
      aHi[0] += __uint_as_float((unsigned)v.x & 0xffff0000u);
      aLo[0] += __uint_as_float((unsigned)v.x << 16);
      aHi[1] += __uint_as_float((unsigned)v.y & 0xffff0000u);
      aLo[1] += __uint_as_float((unsigned)v.y << 16);
      aHi[2] += __uint_as_float((unsigned)v.z & 0xffff0000u);
      aLo[2] += __uint_as_float((unsigned)v.z << 16);
      aHi[3] += __uint_as_float((unsigned)v.w & 0xffff0000u);
      aLo[3] += __uint_as_float((unsigned)v.w << 16);
    }
  }
  #pragma unroll
  for (int m = 8; m < 64; m <<= 1) {
    #pragma unroll
    for (int d = 0; d < 4; ++d) {
      aHi[d] += __shfl_xor(aHi[d], m);
      aLo[d] += __shfl_xor(aLo[d], m);
    }
  }
  if (g8 == 0) {
    float sn = rsqrtf((float)max(deg, 1));
    int4 outv;
    outv.x = (int)(((unsigned)f2bf(aLo[0]*sn)) | ((unsigned)f2bf(aHi[0]*sn) << 16));
    outv.y = (int)(((unsigned)f2bf(aLo[1]*sn)) | ((unsigned)f2bf(aHi[1]*sn) << 16));
    outv.z = (int)(((unsigned)f2bf(aLo[2]*sn)) | ((unsigned)f2bf(aHi[2]*sn) << 16));
    outv.w = (int)(((unsigned)f2bf(aLo[3]*sn)) | ((unsigned)f2bf(aHi[3]*sn) << 16));
    ((int4*)hpreb)[(size_t)npad*8 + fl] = outv;
  }
}

// K4: MFMA GCN GEMM + ReLU + mean pool + fused input projection.
// Also converts w_hh -> fp16 global (whh16, k_lstm staging layout) spread
// over the 200 blocks, halving k_lstm's staging traffic.
__global__ __launch_bounds__(256) void k_gcn(
    const unsigned short* __restrict__ hpreb,
    const float* __restrict__ w_gcn,
    const float* __restrict__ b_gcn,
    const float* __restrict__ w_ih,
    const float* __restrict__ b_ih,
    const float* __restrict__ w_hh,
    int4* __restrict__ whh16,
    float* __restrict__ proj) {
  __shared__ unsigned short wLds[16*64*8];   // 16 KB
  __shared__ float pS[4*DG];
  __shared__ __align__(16) float hgS[DG];
  int t = threadIdx.x, g = blockIdx.x;
  // w_hh fp32 -> fp16 conversion slice (layout: i = k4*512 + r)
  for (int i = g*256 + t; i < 8192; i += N_GRAPHS*256) {
    int k4 = i >> 9, r = i & 511;
    const float4* wp = (const float4*)(w_hh + (size_t)r*HL + k4*8);
    float4 w0 = wp[0], w1 = wp[1];
    half2v p0 = {(_Float16)w0.x, (_Float16)w0.y};
    half2v p1 = {(_Float16)w0.z, (_Float16)w0.w};
    half2v p2 = {(_Float16)w1.x, (_Float16)w1.y};
    half2v p3 = {(_Float16)w1.z, (_Float16)w1.w};
    int4 pk;
    pk.x = __builtin_bit_cast(int, p0); pk.y = __builtin_bit_cast(int, p1);
    pk.z = __builtin_bit_cast(int, p2); pk.w = __builtin_bit_cast(int, p3);
    whh16[i] = pk;
  }
  for (int idx = t; idx < 16*64; idx += 256) {
    int f = idx >> 6, l = idx & 63;
    int h = f & 1, nt = f >> 1;
    int kbase = h*32 + (l >> 4)*8;
    int n = nt*16 + (l & 15);
    #pragma unroll
    for (int j = 0; j < 8; ++j)
      wLds[idx*8 + j] = f2bf(w_gcn[(kbase + j)*DG + n]);
  }
  __syncthreads();
  int w = t >> 6, lane = t & 63;
  int quad = lane >> 4, l15 = lane & 15;
  float bcol[8];
  #pragma unroll
  for (int nt = 0; nt < 8; ++nt) bcol[nt] = b_gcn[nt*16 + l15];
  float psum[8] = {0.f,0.f,0.f,0.f,0.f,0.f,0.f,0.f};
  const unsigned short* hb = hpreb + (size_t)g*NPGP*DIN;
  for (int i = 0; i < 8; ++i) {
    int rt = w + 4*i;
    int row0 = rt*16;
    const short8* aptr = (const short8*)(hb + (size_t)(row0 + l15)*DIN + quad*8);
    short8 a0 = aptr[0];
    short8 a1 = aptr[4];
    #pragma unroll
    for (int nt = 0; nt < 8; ++nt) {
      short8 b0 = *((const short8*)&wLds[((nt*2+0)*64 + lane)*8]);
      short8 b1 = *((const short8*)&wLds[((nt*2+1)*64 + lane)*8]);
      float4v acc = {0.f, 0.f, 0.f, 0.f};
      acc = __builtin_amdgcn_mfma_f32_16x16x32_bf16(a0, b0, acc, 0, 0, 0);
      acc = __builtin_amdgcn_mfma_f32_16x16x32_bf16(a1, b1, acc, 0, 0, 0);
      #pragma unroll
      for (int r = 0; r < 4; ++r) {
        int node = row0 + quad*4 + r;
        float v = acc[r] + bcol[nt];
        psum[nt] += (node < NPG) ? fmaxf(v, 0.f) : 0.f;
      }
    }
  }
  #pragma unroll
  for (int nt = 0; nt < 8; ++nt) {
    float v = psum[nt];
    v += __shfl_xor(v, 16);
    v += __shfl_xor(v, 32);
    if (lane < 16) pS[w*DG + nt*16 + lane] = v;
  }
  __syncthreads();
  if (t < DG)
    hgS[t] = (pS[t] + pS[DG+t] + pS[2*DG+t] + pS[3*DG+t]) * (1.0f/NPG);
  __syncthreads();
  for (int r = t; r < G4; r += 256) {
    const float4* wr = (const float4*)(w_ih + (size_t)r*HL);
    const float4* hv = (const float4*)hgS;
    float acc = b_ih[r];
    #pragma unroll
    for (int k4 = 0; k4 < 32; ++k4) {
      float4 w4 = wr[k4]; float4 h4 = hv[k4];
      acc += w4.x*h4.x + w4.y*h4.y + w4.z*h4.z + w4.w*h4.w;
    }
    proj[(size_t)g*G4 + r] = acc;
  }
}

// K5: LSTM — w_hh fp16 CU-resident in LDS (staged from pre-converted whh16);
// h packed fp16; fp32 accumulation via v_dot2_f32_f16; gates/c fp32.
__global__ __launch_bounds__(512) void k_lstm(const float* __restrict__ proj,
    const int4* __restrict__ whh16, const float* __restrict__ b_hh,
    const float* __restrict__ w_fc, const float* __restrict__ b_fc,
    float* __restrict__ out) {
  __shared__ int4 wL[16*512];        // 128 KB: [k4][r] = 8 fp16 of w_hh[r][k4*8..]
  __shared__ float gS[G4];
  __shared__ __align__(16) int4 hPi[16];  // 128 fp16 packed h state
  int b = blockIdx.x, t = threadIdx.x;
  for (int i = t; i < 16*512; i += 512) wL[i] = whh16[i];
  if (t < 16) hPi[t] = make_int4(0,0,0,0);
  float bh = b_hh[t];
  float c0 = 0.f, c1 = 0.f;
  __syncthreads();
  for (int l = 0; l < SEQ; ++l) {
    float acc = proj[(size_t)(b+l)*G4 + t] + bh;
    #pragma unroll
    for (int k4 = 0; k4 < 16; ++k4) {
      int4 wv = wL[(k4 << 9) + t];
      int4 hv = hPi[k4];
      acc = h2dot(__builtin_bit_cast(half2v, wv.x), __builtin_bit_cast(half2v, hv.x), acc);
      acc = h2dot(__builtin_bit_cast(half2v, wv.y), __builtin_bit_cast(half2v, hv.y), acc);
      acc = h2dot(__builtin_bit_cast(half2v, wv.z), __builtin_bit_cast(half2v, hv.z), acc);
      acc = h2dot(__builtin_bit_cast(half2v, wv.w), __builtin_bit_cast(half2v, hv.w), acc);
    }
    gS[t] = acc;
    __syncthreads();
    if (t < 64) {
      int j0 = 2*t, j1 = 2*t + 1;
      float i0 = sigmoidf_(gS[j0]),      i1 = sigmoidf_(gS[j1]);
      float f0 = sigmoidf_(gS[HL+j0]),   f1 = sigmoidf_(gS[HL+j1]);
      float g0 = tanhf(gS[2*HL+j0]),     g1 = tanhf(gS[2*HL+j1]);
      float o0 = sigmoidf_(gS[3*HL+j0]), o1 = sigmoidf_(gS[3*HL+j1]);
      c0 = f0*c0 + i0*g0;
      c1 = f1*c1 + i1*g1;
      float h0 = o0 * tanhf(c0);
      float h1 = o1 * tanhf(c1);
      half2v hp = {(_Float16)h0, (_Float16)h1};
      ((int*)hPi)[t] = __builtin_bit_cast(int, hp);
      if (l == SEQ-1) {
        float s = h0*w_fc[j0] + h1*w_fc[j1];
        #pragma unroll
        for (int off = 32; off > 0; off >>= 1) s += __shfl_down(s, off);
        if (t == 0) out[b] = s + b_fc[0];
      }
    }
    __syncthreads();
  }
}

extern "C" void kernel_launch(void* const* d_in, const int* in_sizes, int n_in,
                              void* d_out, int out_size, void* d_ws, size_t ws_size,
                              hipStream_t stream) {
  const float* x     = (const float*)d_in[0];
  const int*   src   = (const int*)d_in[1];
  const int*   dst   = (const int*)d_in[2];
  const float* w_gcn = (const float*)d_in[4];
  const float* b_gcn = (const float*)d_in[5];
  const float* w_ih  = (const float*)d_in[6];
  const float* w_hh  = (const float*)d_in[7];
  const float* b_ih  = (const float*)d_in[8];
  const float* b_hh  = (const float*)d_in[9];
  const float* w_fc  = (const float*)d_in[10];
  const float* b_fc  = (const float*)d_in[11];
  float* out = (float*)d_out;

  char* ws = (char*)d_ws;
  size_t off = 0;
  auto alloc = [&](size_t bytes) -> void* {
    void* p = ws + off; off += (bytes + 255) & ~(size_t)255; return p;
  };
  int* cnt2    = (int*)alloc((size_t)N_GRAPHS*NPART*4);
  int* part    = (int*)alloc((size_t)N_GRAPHS*GCAP*4);
  unsigned short* sorted_all = (unsigned short*)alloc((size_t)N_GRAPHS*SCAP*2);
  int* e_end   = (int*)alloc((size_t)N_NODES_*4);
  int* e_deg   = (int*)alloc((size_t)N_NODES_*4);
  ushort4* xsb = (ushort4*)alloc((size_t)N_NODES_*DIN*2);
  unsigned short* hpreb = (unsigned short*)alloc((size_t)N_GRAPHS*NPGP*DIN*2);
  int4* whh16  = (int4*)alloc((size_t)8192*16);
  float* proj  = (float*)alloc((size_t)N_GRAPHS*G4*4);
  (void)ws_size; (void)in_sizes; (void)n_in; (void)out_size;

  k_part<<<NPART, 256, 0, stream>>>(src, dst, cnt2, part);
  k_sort<<<N_GRAPHS, 512, 0, stream>>>(cnt2, part, x, sorted_all, e_end, e_deg, xsb);
  k_agg<<<(N_GRAPHS*NPGP)/4, 256, 0, stream>>>((const int4*)xsb, e_end, e_deg, sorted_all, hpreb);
  k_gcn<<<N_GRAPHS, 256, 0, stream>>>(hpreb, w_gcn, b_gcn, w_ih, b_ih, w_hh, whh16, proj);
  k_lstm<<<BWIN, 512, 0, stream>>>(proj, whh16, b_hh, w_fc, b_fc, out);
}

// Round 15
// 224.559 us; speedup vs baseline: 1.0785x; 1.0534x over previous
//
#include <hip/hip_runtime.h>
#include <hip/hip_bf16.h>

#define N_GRAPHS 200
#define NPG      500
#define NPGP     512                   // padded nodes per graph (MFMA tiles)
#define N_NODES_ 100000
#define N_EDGES_ 1600000
#define DIN      64
#define DG       128
#define SEQ      20
#define HL       128
#define G4       512
#define BWIN     (N_GRAPHS - SEQ + 1)  // 181
#define NPART    512
#define EPB      (N_EDGES_/NPART)      // 3125
#define SLOTS    48                    // LDS bucket slots/graph/block (mean 15.6 + 8.2 sigma)
#define CAP      9216                  // per-graph edge segment capacity

typedef __attribute__((ext_vector_type(8))) short short8;
typedef __attribute__((ext_vector_type(4))) float float4v;
typedef __attribute__((ext_vector_type(2))) _Float16 half2v;

__device__ __forceinline__ float sigmoidf_(float v){ return 1.0f/(1.0f+expf(-v)); }

// fp32 -> bf16 round-to-nearest-even
__device__ __forceinline__ unsigned short f2bf(float f) {
  unsigned int u = __float_as_uint(f);
  u += 0x7fffu + ((u >> 16) & 1u);
  return (unsigned short)(u >> 16);
}

__device__ __forceinline__ float h2dot(half2v a, half2v b, float c) {
#if __has_builtin(__builtin_amdgcn_fdot2)
  return __builtin_amdgcn_fdot2(a, b, c, false);
#else
  return c + (float)a.x*(float)b.x + (float)a.y*(float)b.y;
#endif
}

// K1: scan-free partition into contiguous per-graph segments part[g*CAP ...].
// LDS bucket (48 slots/graph) -> one device atomicAdd per (block,graph) to
// reserve a base -> wave-per-graph coalesced flush. 512 blocks for 2x CU
// coverage vs round-12's 256. (Round-14's fixed-cell variant regressed: cell
// compaction in k_sort cost more than the saved memset dispatch.)
__global__ __launch_bounds__(256) void k_part(const int* __restrict__ src,
                                              const int* __restrict__ dst,
                                              int* __restrict__ gcount,
                                              int* __restrict__ part) {
  __shared__ int cnt[N_GRAPHS];
  __shared__ int base[N_GRAPHS];
  __shared__ int buf[N_GRAPHS][SLOTS];   // 38.4 KB
  int b = blockIdx.x, t = threadIdx.x;
  for (int g = t; g < N_GRAPHS; g += 256) cnt[g] = 0;
  __syncthreads();
  int e0 = b*EPB;
  for (int i = t; i < EPB; i += 256) {
    int s = src[e0+i], d = dst[e0+i];
    int g = s / NPG;
    int sl = s - g*NPG, dl = d - g*NPG;
    int pk = (sl << 9) | dl;
    int pos = atomicAdd(&cnt[g], 1);
    if (pos < SLOTS) buf[g][pos] = pk;
    else {                                // rare overflow (>8 sigma)
      int gp = atomicAdd(&gcount[g], 1);
      part[g*CAP + gp] = pk;
    }
  }
  __syncthreads();
  if (t < N_GRAPHS) base[t] = atomicAdd(&gcount[t], min(cnt[t], SLOTS));
  __syncthreads();
  int w = t >> 6, lane = t & 63;
  for (int g = w; g < N_GRAPHS; g += 4) {
    int n = min(cnt[g], SLOTS);
    int ba = g*CAP + base[g];
    if (lane < n) part[ba + lane] = buf[g][lane];   // n <= 48 < 64: one pass
  }
}

// K2: per-graph counting sort (dense contiguous segment) -> sorted src list +
// node metadata + fused xprep (xsb = bf16(x*so)).
__global__ __launch_bounds__(512) void k_sort(const int* __restrict__ gcount,
    const int* __restrict__ part, const float* __restrict__ x,
    unsigned short* __restrict__ sorted_all,
    int* __restrict__ e_end, int* __restrict__ e_deg,
    ushort4* __restrict__ xsb) {
  __shared__ int indeg[NPG], outdeg[NPG], off[NPG];
  __shared__ float soS[NPG];
  __shared__ int sA[512], sB[512];
  int g = blockIdx.x, t = threadIdx.x;
  int seg0 = g*CAP;
  int seg1 = seg0 + gcount[g];
  if (t < NPG) { indeg[t] = 0; outdeg[t] = 0; }
  __syncthreads();
  for (int e = seg0 + t; e < seg1; e += 512) {
    int p = part[e];
    atomicAdd(&indeg[p & 511], 1);
    atomicAdd(&outdeg[p >> 9], 1);
  }
  __syncthreads();
  int v = (t < NPG) ? indeg[t] : 0;
  sA[t] = v; __syncthreads();
  int* cur = sA; int* nxt = sB;
  for (int o = 1; o < 512; o <<= 1) {
    nxt[t] = cur[t] + ((t >= o) ? cur[t-o] : 0);
    __syncthreads();
    int* tmp = cur; cur = nxt; nxt = tmp;
  }
  if (t < NPG) {
    off[t] = cur[t] - v;
    soS[t] = rsqrtf((float)max(outdeg[t], 1));
    e_deg[g*NPG + t] = indeg[t];
  }
  __syncthreads();
  for (int e = seg0 + t; e < seg1; e += 512) {
    int p = part[e];
    int pos = atomicAdd(&off[p & 511], 1);
    sorted_all[seg0 + pos] = (unsigned short)(p >> 9);
  }
  __syncthreads();
  if (t < NPG) e_end[g*NPG + t] = seg0 + off[t];   // inclusive end
  __syncthreads();
  // fused xprep
  const float4* xg = ((const float4*)x) + (size_t)g*8000;   // 500*16
  ushort4* og = xsb + (size_t)g*8000;
  for (int i = t; i < 8000; i += 512) {
    float4 vv = xg[i];
    float s = soS[i >> 4];
    ushort4 u;
    u.x = f2bf(vv.x*s); u.y = f2bf(vv.y*s); u.z = f2bf(vv.z*s); u.w = f2bf(vv.w*s);
    og[i] = u;
  }
}

// K3: aggregation — wave per node slot; 8 lanes per edge (int4 = 8 bf16),
// 2-edge unroll per group (deg~16: 8 groups x 2 covers one iteration with all
// groups live; 4-unroll left half the groups predicated off). Packed-bf16
// accumulate (exact). XCD swizzle: g % 8 == xcd.
__global__ __launch_bounds__(256) void k_agg(const int4* __restrict__ xsb,
    const int* __restrict__ e_end, const int* __restrict__ e_deg,
    const unsigned short* __restrict__ sorted_all,
    unsigned short* __restrict__ hpreb) {
  int b = blockIdx.x;
  int xcd = b & 7;
  int i_ = b >> 3;                       // 0..3199
  int g = (i_ >> 7)*8 + xcd;             // g % 8 == xcd
  int t = threadIdx.x;
  int nl = ((i_ & 127) << 2) + (t >> 6); // node slot 0..511 within graph
  int npad = g*NPGP + nl;
  int lane = t & 63, g8 = lane >> 3, fl = lane & 7;
  if (nl >= NPG) {                       // pad rows -> zeros
    if (g8 == 0) {
      int4 z = make_int4(0,0,0,0);
      ((int4*)hpreb)[(size_t)npad*8 + fl] = z;
    }
    return;
  }
  int n = g*NPG + nl;
  int end = e_end[n], deg = e_deg[n], start = end - deg;
  const int4* xg = xsb + (size_t)g*4000;      // 500 rows * 8 int4
  float aHi[4] = {0.f,0.f,0.f,0.f};
  float aLo[4] = {0.f,0.f,0.f,0.f};
  for (int i = start + (g8 << 1); i < end; i += 16) {
    int s0 = (int)sorted_all[i];
    int4 v = xg[s0*8 + fl];
    aHi[0] += __uint_as_float((unsigned)v.x & 0xffff0000u);
    aLo[0] += __uint_as_float((unsigned)v.x << 16);
    aHi[1] += __uint_as_float((unsigned)v.y & 0xffff0000u);
    aLo[1] += __uint_as_float((unsigned)v.y << 16);
    aHi[2] += __uint_as_float((unsigned)v.z & 0xffff0000u);
    aLo[2] += __uint_as_float((unsigned)v.z << 16);
    aHi[3] += __uint_as_float((unsigned)v.w & 0xffff0000u);
    aLo[3] += __uint_as_float((unsigned)v.w << 16);
    if (i + 1 < end) {
      int s1 = (int)sorted_all[i+1];
      int4 w = xg[s1*8 + fl];
      aHi[0] += __uint_as_float((unsigned)w.x & 0xffff0000u);
      aLo[0] += __uint_as_float((unsigned)w.x << 16);
      aHi[1] += __uint_as_float((unsigned)w.y & 0xffff0000u);
      aLo[1] += __uint_as_float((unsigned)w.y << 16);
      aHi[2] += __uint_as_float((unsigned)w.z & 0xffff0000u);
      aLo[2] += __uint_as_float((unsigned)w.z << 16);
      aHi[3] += __uint_as_float((unsigned)w.w & 0xffff0000u);
      aLo[3] += __uint_as_float((unsigned)w.w << 16);
    }
  }
  #pragma unroll
  for (int m = 8; m < 64; m <<= 1) {
    #pragma unroll
    for (int d = 0; d < 4; ++d) {
      aHi[d] += __shfl_xor(aHi[d], m);
      aLo[d] += __shfl_xor(aLo[d], m);
    }
  }
  if (g8 == 0) {
    float sn = rsqrtf((float)max(deg, 1));
    int4 outv;
    outv.x = (int)(((unsigned)f2bf(aLo[0]*sn)) | ((unsigned)f2bf(aHi[0]*sn) << 16));
    outv.y = (int)(((unsigned)f2bf(aLo[1]*sn)) | ((unsigned)f2bf(aHi[1]*sn) << 16));
    outv.z = (int)(((unsigned)f2bf(aLo[2]*sn)) | ((unsigned)f2bf(aHi[2]*sn) << 16));
    outv.w = (int)(((unsigned)f2bf(aLo[3]*sn)) | ((unsigned)f2bf(aHi[3]*sn) << 16));
    ((int4*)hpreb)[(size_t)npad*8 + fl] = outv;
  }
}

// K4: MFMA GCN GEMM + ReLU + mean pool + fused input projection.
// Also converts w_hh -> fp16 global (whh16) spread over 200 blocks, halving
// k_lstm's staging traffic (verified-cheap delta from round 14).
__global__ __launch_bounds__(256) void k_gcn(
    const unsigned short* __restrict__ hpreb,
    const float* __restrict__ w_gcn,
    const float* __restrict__ b_gcn,
    const float* __restrict__ w_ih,
    const float* __restrict__ b_ih,
    const float* __restrict__ w_hh,
    int4* __restrict__ whh16,
    float* __restrict__ proj) {
  __shared__ unsigned short wLds[16*64*8];   // 16 KB
  __shared__ float pS[4*DG];
  __shared__ __align__(16) float hgS[DG];
  int t = threadIdx.x, g = blockIdx.x;
  // w_hh fp32 -> fp16 conversion slice (layout: i = k4*512 + r)
  for (int i = g*256 + t; i < 8192; i += N_GRAPHS*256) {
    int k4 = i >> 9, r = i & 511;
    const float4* wp = (const float4*)(w_hh + (size_t)r*HL + k4*8);
    float4 w0 = wp[0], w1 = wp[1];
    half2v p0 = {(_Float16)w0.x, (_Float16)w0.y};
    half2v p1 = {(_Float16)w0.z, (_Float16)w0.w};
    half2v p2 = {(_Float16)w1.x, (_Float16)w1.y};
    half2v p3 = {(_Float16)w1.z, (_Float16)w1.w};
    int4 pk;
    pk.x = __builtin_bit_cast(int, p0); pk.y = __builtin_bit_cast(int, p1);
    pk.z = __builtin_bit_cast(int, p2); pk.w = __builtin_bit_cast(int, p3);
    whh16[i] = pk;
  }
  for (int idx = t; idx < 16*64; idx += 256) {
    int f = idx >> 6, l = idx & 63;
    int h = f & 1, nt = f >> 1;
    int kbase = h*32 + (l >> 4)*8;
    int n = nt*16 + (l & 15);
    #pragma unroll
    for (int j = 0; j < 8; ++j)
      wLds[idx*8 + j] = f2bf(w_gcn[(kbase + j)*DG + n]);
  }
  __syncthreads();
  int w = t >> 6, lane = t & 63;
  int quad = lane >> 4, l15 = lane & 15;
  float bcol[8];
  #pragma unroll
  for (int nt = 0; nt < 8; ++nt) bcol[nt] = b_gcn[nt*16 + l15];
  float psum[8] = {0.f,0.f,0.f,0.f,0.f,0.f,0.f,0.f};
  const unsigned short* hb = hpreb + (size_t)g*NPGP*DIN;
  for (int i = 0; i < 8; ++i) {
    int rt = w + 4*i;
    int row0 = rt*16;
    const short8* aptr = (const short8*)(hb + (size_t)(row0 + l15)*DIN + quad*8);
    short8 a0 = aptr[0];
    short8 a1 = aptr[4];
    #pragma unroll
    for (int nt = 0; nt < 8; ++nt) {
      short8 b0 = *((const short8*)&wLds[((nt*2+0)*64 + lane)*8]);
      short8 b1 = *((const short8*)&wLds[((nt*2+1)*64 + lane)*8]);
      float4v acc = {0.f, 0.f, 0.f, 0.f};
      acc = __builtin_amdgcn_mfma_f32_16x16x32_bf16(a0, b0, acc, 0, 0, 0);
      acc = __builtin_amdgcn_mfma_f32_16x16x32_bf16(a1, b1, acc, 0, 0, 0);
      #pragma unroll
      for (int r = 0; r < 4; ++r) {
        int node = row0 + quad*4 + r;
        float v = acc[r] + bcol[nt];
        psum[nt] += (node < NPG) ? fmaxf(v, 0.f) : 0.f;
      }
    }
  }
  #pragma unroll
  for (int nt = 0; nt < 8; ++nt) {
    float v = psum[nt];
    v += __shfl_xor(v, 16);
    v += __shfl_xor(v, 32);
    if (lane < 16) pS[w*DG + nt*16 + lane] = v;
  }
  __syncthreads();
  if (t < DG)
    hgS[t] = (pS[t] + pS[DG+t] + pS[2*DG+t] + pS[3*DG+t]) * (1.0f/NPG);
  __syncthreads();
  for (int r = t; r < G4; r += 256) {
    const float4* wr = (const float4*)(w_ih + (size_t)r*HL);
    const float4* hv = (const float4*)hgS;
    float acc = b_ih[r];
    #pragma unroll
    for (int k4 = 0; k4 < 32; ++k4) {
      float4 w4 = wr[k4]; float4 h4 = hv[k4];
      acc += w4.x*h4.x + w4.y*h4.y + w4.z*h4.z + w4.w*h4.w;
    }
    proj[(size_t)g*G4 + r] = acc;
  }
}

// K5: LSTM — w_hh fp16 CU-resident in LDS (staged from pre-converted whh16);
// h packed fp16; fp32 accumulation via v_dot2_f32_f16; gates/c fp32.
__global__ __launch_bounds__(512) void k_lstm(const float* __restrict__ proj,
    const int4* __restrict__ whh16, const float* __restrict__ b_hh,
    const float* __restrict__ w_fc, const float* __restrict__ b_fc,
    float* __restrict__ out) {
  __shared__ int4 wL[16*512];        // 128 KB: [k4][r] = 8 fp16 of w_hh[r][k4*8..]
  __shared__ float gS[G4];
  __shared__ __align__(16) int4 hPi[16];  // 128 fp16 packed h state
  int b = blockIdx.x, t = threadIdx.x;
  for (int i = t; i < 16*512; i += 512) wL[i] = whh16[i];
  if (t < 16) hPi[t] = make_int4(0,0,0,0);
  float bh = b_hh[t];
  float c0 = 0.f, c1 = 0.f;
  __syncthreads();
  for (int l = 0; l < SEQ; ++l) {
    float acc = proj[(size_t)(b+l)*G4 + t] + bh;
    #pragma unroll
    for (int k4 = 0; k4 < 16; ++k4) {
      int4 wv = wL[(k4 << 9) + t];
      int4 hv = hPi[k4];
      acc = h2dot(__builtin_bit_cast(half2v, wv.x), __builtin_bit_cast(half2v, hv.x), acc);
      acc = h2dot(__builtin_bit_cast(half2v, wv.y), __builtin_bit_cast(half2v, hv.y), acc);
      acc = h2dot(__builtin_bit_cast(half2v, wv.z), __builtin_bit_cast(half2v, hv.z), acc);
      acc = h2dot(__builtin_bit_cast(half2v, wv.w), __builtin_bit_cast(half2v, hv.w), acc);
    }
    gS[t] = acc;
    __syncthreads();
    if (t < 64) {
      int j0 = 2*t, j1 = 2*t + 1;
      float i0 = sigmoidf_(gS[j0]),      i1 = sigmoidf_(gS[j1]);
      float f0 = sigmoidf_(gS[HL+j0]),   f1 = sigmoidf_(gS[HL+j1]);
      float g0 = tanhf(gS[2*HL+j0]),     g1 = tanhf(gS[2*HL+j1]);
      float o0 = sigmoidf_(gS[3*HL+j0]), o1 = sigmoidf_(gS[3*HL+j1]);
      c0 = f0*c0 + i0*g0;
      c1 = f1*c1 + i1*g1;
      float h0 = o0 * tanhf(c0);
      float h1 = o1 * tanhf(c1);
      half2v hp = {(_Float16)h0, (_Float16)h1};
      ((int*)hPi)[t] = __builtin_bit_cast(int, hp);
      if (l == SEQ-1) {
        float s = h0*w_fc[j0] + h1*w_fc[j1];
        #pragma unroll
        for (int off = 32; off > 0; off >>= 1) s += __shfl_down(s, off);
        if (t == 0) out[b] = s + b_fc[0];
      }
    }
    __syncthreads();
  }
}

extern "C" void kernel_launch(void* const* d_in, const int* in_sizes, int n_in,
                              void* d_out, int out_size, void* d_ws, size_t ws_size,
                              hipStream_t stream) {
  const float* x     = (const float*)d_in[0];
  const int*   src   = (const int*)d_in[1];
  const int*   dst   = (const int*)d_in[2];
  const float* w_gcn = (const float*)d_in[4];
  const float* b_gcn = (const float*)d_in[5];
  const float* w_ih  = (const float*)d_in[6];
  const float* w_hh  = (const float*)d_in[7];
  const float* b_ih  = (const float*)d_in[8];
  const float* b_hh  = (const float*)d_in[9];
  const float* w_fc  = (const float*)d_in[10];
  const float* b_fc  = (const float*)d_in[11];
  float* out = (float*)d_out;

  char* ws = (char*)d_ws;
  size_t off = 0;
  auto alloc = [&](size_t bytes) -> void* {
    void* p = ws + off; off += (bytes + 255) & ~(size_t)255; return p;
  };
  int* gcount  = (int*)alloc((size_t)N_GRAPHS*4);
  int* part    = (int*)alloc((size_t)N_GRAPHS*CAP*4);
  unsigned short* sorted_all = (unsigned short*)alloc((size_t)N_GRAPHS*CAP*2);
  int* e_end   = (int*)alloc((size_t)N_NODES_*4);
  int* e_deg   = (int*)alloc((size_t)N_NODES_*4);
  ushort4* xsb = (ushort4*)alloc((size_t)N_NODES_*DIN*2);
  unsigned short* hpreb = (unsigned short*)alloc((size_t)N_GRAPHS*NPGP*DIN*2);
  int4* whh16  = (int4*)alloc((size_t)8192*16);
  float* proj  = (float*)alloc((size_t)N_GRAPHS*G4*4);
  (void)ws_size; (void)in_sizes; (void)n_in; (void)out_size;

  hipMemsetAsync(gcount, 0, (size_t)N_GRAPHS*4, stream);
  k_part<<<NPART, 256, 0, stream>>>(src, dst, gcount, part);
  k_sort<<<N_GRAPHS, 512, 0, stream>>>(gcount, part, x, sorted_all, e_end, e_deg, xsb);
  k_agg<<<(N_GRAPHS*NPGP)/4, 256, 0, stream>>>((const int4*)xsb, e_end, e_deg, sorted_all, hpreb);
  k_gcn<<<N_GRAPHS, 256, 0, stream>>>(hpreb, w_gcn, b_gcn, w_ih, b_ih, w_hh, whh16, proj);
  k_lstm<<<BWIN, 512, 0, stream>>>(proj, whh16, b_hh, w_fc, b_fc, out);
}

// Round 16
// 215.039 us; speedup vs baseline: 1.1263x; 1.0443x over previous
//
#include <hip/hip_runtime.h>
#include <hip/hip_bf16.h>

#define N_GRAPHS 200
#define NPG      500
#define NPGP     512                   // padded nodes per graph (MFMA tiles)
#define N_NODES_ 100000
#define N_EDGES_ 1600000
#define DIN      64
#define DG       128
#define SEQ      20
#define HL       128
#define G4       512
#define BWIN     (N_GRAPHS - SEQ + 1)  // 181
#define NPART    512
#define EPB      (N_EDGES_/NPART)      // 3125
#define SLOTS    48                    // LDS bucket slots/graph/block (mean 15.6 + 8.2 sigma)
#define CAP      9216                  // per-graph edge segment capacity

typedef __attribute__((ext_vector_type(8))) short short8;
typedef __attribute__((ext_vector_type(4))) float float4v;
typedef __attribute__((ext_vector_type(2))) _Float16 half2v;

__device__ __forceinline__ float sigmoidf_(float v){ return 1.0f/(1.0f+expf(-v)); }

// fp32 -> bf16 round-to-nearest-even
__device__ __forceinline__ unsigned short f2bf(float f) {
  unsigned int u = __float_as_uint(f);
  u += 0x7fffu + ((u >> 16) & 1u);
  return (unsigned short)(u >> 16);
}

__device__ __forceinline__ float h2dot(half2v a, half2v b, float c) {
#if __has_builtin(__builtin_amdgcn_fdot2)
  return __builtin_amdgcn_fdot2(a, b, c, false);
#else
  return c + (float)a.x*(float)b.x + (float)a.y*(float)b.y;
#endif
}

// K1: scan-free partition into contiguous per-graph segments part[g*CAP ...].
// LDS bucket (48 slots/graph) -> one device atomicAdd per (block,graph) to
// reserve a base -> wave-per-graph coalesced flush. 512 blocks.
__global__ __launch_bounds__(256) void k_part(const int* __restrict__ src,
                                              const int* __restrict__ dst,
                                              int* __restrict__ gcount,
                                              int* __restrict__ part) {
  __shared__ int cnt[N_GRAPHS];
  __shared__ int base[N_GRAPHS];
  __shared__ int buf[N_GRAPHS][SLOTS];   // 38.4 KB
  int b = blockIdx.x, t = threadIdx.x;
  for (int g = t; g < N_GRAPHS; g += 256) cnt[g] = 0;
  __syncthreads();
  int e0 = b*EPB;
  for (int i = t; i < EPB; i += 256) {
    int s = src[e0+i], d = dst[e0+i];
    int g = s / NPG;
    int sl = s - g*NPG, dl = d - g*NPG;
    int pk = (sl << 9) | dl;
    int pos = atomicAdd(&cnt[g], 1);
    if (pos < SLOTS) buf[g][pos] = pk;
    else {                                // rare overflow (>8 sigma)
      int gp = atomicAdd(&gcount[g], 1);
      part[g*CAP + gp] = pk;
    }
  }
  __syncthreads();
  if (t < N_GRAPHS) base[t] = atomicAdd(&gcount[t], min(cnt[t], SLOTS));
  __syncthreads();
  int w = t >> 6, lane = t & 63;
  for (int g = w; g < N_GRAPHS; g += 4) {
    int n = min(cnt[g], SLOTS);
    int ba = g*CAP + base[g];
    if (lane < n) part[ba + lane] = buf[g][lane];   // n <= 48 < 64: one pass
  }
}

// K2: per-graph counting sort (dense contiguous segment) -> sorted src list +
// node metadata + fused xprep (xsb = bf16(x*so)).
__global__ __launch_bounds__(512) void k_sort(const int* __restrict__ gcount,
    const int* __restrict__ part, const float* __restrict__ x,
    unsigned short* __restrict__ sorted_all,
    int* __restrict__ e_end, int* __restrict__ e_deg,
    ushort4* __restrict__ xsb) {
  __shared__ int indeg[NPG], outdeg[NPG], off[NPG];
  __shared__ float soS[NPG];
  __shared__ int sA[512], sB[512];
  int g = blockIdx.x, t = threadIdx.x;
  int seg0 = g*CAP;
  int seg1 = seg0 + gcount[g];
  if (t < NPG) { indeg[t] = 0; outdeg[t] = 0; }
  __syncthreads();
  for (int e = seg0 + t; e < seg1; e += 512) {
    int p = part[e];
    atomicAdd(&indeg[p & 511], 1);
    atomicAdd(&outdeg[p >> 9], 1);
  }
  __syncthreads();
  int v = (t < NPG) ? indeg[t] : 0;
  sA[t] = v; __syncthreads();
  int* cur = sA; int* nxt = sB;
  for (int o = 1; o < 512; o <<= 1) {
    nxt[t] = cur[t] + ((t >= o) ? cur[t-o] : 0);
    __syncthreads();
    int* tmp = cur; cur = nxt; nxt = tmp;
  }
  if (t < NPG) {
    off[t] = cur[t] - v;
    soS[t] = rsqrtf((float)max(outdeg[t], 1));
    e_deg[g*NPG + t] = indeg[t];
  }
  __syncthreads();
  for (int e = seg0 + t; e < seg1; e += 512) {
    int p = part[e];
    int pos = atomicAdd(&off[p & 511], 1);
    sorted_all[seg0 + pos] = (unsigned short)(p >> 9);
  }
  __syncthreads();
  if (t < NPG) e_end[g*NPG + t] = seg0 + off[t];   // inclusive end
  __syncthreads();
  // fused xprep
  const float4* xg = ((const float4*)x) + (size_t)g*8000;   // 500*16
  ushort4* og = xsb + (size_t)g*8000;
  for (int i = t; i < 8000; i += 512) {
    float4 vv = xg[i];
    float s = soS[i >> 4];
    ushort4 u;
    u.x = f2bf(vv.x*s); u.y = f2bf(vv.y*s); u.z = f2bf(vv.z*s); u.w = f2bf(vv.w*s);
    og[i] = u;
  }
}

// K3: aggregation v4 — the graph's whole 64 KB xsb slice staged into LDS, then
// gathers hit LDS (bandwidth-minimal: a wave ds_read_b128 moves 1024 B in >=8
// bank-cycles for ANY pattern, so no swizzle needed). Each 8-lane group OWNS
// one node slot end-to-end: no cross-group shfl reduce, direct 128 B row
// write. 4 blocks/graph x 512 thr, 64 KB LDS -> 2 blocks/CU (round-13's mega
// failed on 1 block/CU; this keeps occupancy). XCD swizzle: a graph's 4
// blocks share one XCD for staging L2 reuse.
__global__ __launch_bounds__(512) void k_agg(const int4* __restrict__ xsb,
    const int* __restrict__ e_end, const int* __restrict__ e_deg,
    const unsigned short* __restrict__ sorted_all,
    unsigned short* __restrict__ hpreb) {
  __shared__ int4 xLds[4000];            // 500 rows x 8 int4 = 64000 B
  int b = blockIdx.x;
  int xcd = b & 7, q = b >> 3;           // q 0..99
  int g = xcd*25 + (q >> 2);             // graph; 4 blocks/graph on one XCD
  int p = q & 3;                         // part: slots p*128 .. p*128+127
  int t = threadIdx.x;
  const int4* xg = xsb + (size_t)g*4000;
  for (int i = t; i < 4000; i += 512) xLds[i] = xg[i];
  __syncthreads();
  int w8 = t >> 6, lane = t & 63, g8 = lane >> 3, fl = lane & 7;
  #pragma unroll
  for (int s0 = 0; s0 < 16; s0 += 8) {
    int nl = p*128 + w8*16 + s0 + g8;
    int npad = g*NPGP + nl;
    if (nl >= NPG) {                     // pad rows -> zeros
      ((int4*)hpreb)[(size_t)npad*8 + fl] = make_int4(0,0,0,0);
      continue;
    }
    int n = g*NPG + nl;
    int end = e_end[n], deg = e_deg[n], start = end - deg;
    float aHi[4] = {0.f,0.f,0.f,0.f};
    float aLo[4] = {0.f,0.f,0.f,0.f};
    for (int i = start; i < end; i += 2) {
      int se = (int)sorted_all[i];
      int4 v = xLds[(se << 3) + fl];
      aHi[0] += __uint_as_float((unsigned)v.x & 0xffff0000u);
      aLo[0] += __uint_as_float((unsigned)v.x << 16);
      aHi[1] += __uint_as_float((unsigned)v.y & 0xffff0000u);
      aLo[1] += __uint_as_float((unsigned)v.y << 16);
      aHi[2] += __uint_as_float((unsigned)v.z & 0xffff0000u);
      aLo[2] += __uint_as_float((unsigned)v.z << 16);
      aHi[3] += __uint_as_float((unsigned)v.w & 0xffff0000u);
      aLo[3] += __uint_as_float((unsigned)v.w << 16);
      if (i + 1 < end) {
        int se1 = (int)sorted_all[i+1];
        int4 w = xLds[(se1 << 3) + fl];
        aHi[0] += __uint_as_float((unsigned)w.x & 0xffff0000u);
        aLo[0] += __uint_as_float((unsigned)w.x << 16);
        aHi[1] += __uint_as_float((unsigned)w.y & 0xffff0000u);
        aLo[1] += __uint_as_float((unsigned)w.y << 16);
        aHi[2] += __uint_as_float((unsigned)w.z & 0xffff0000u);
        aLo[2] += __uint_as_float((unsigned)w.z << 16);
        aHi[3] += __uint_as_float((unsigned)w.w & 0xffff0000u);
        aLo[3] += __uint_as_float((unsigned)w.w << 16);
      }
    }
    float sn = rsqrtf((float)max(deg, 1));
    int4 outv;
    outv.x = (int)(((unsigned)f2bf(aLo[0]*sn)) | ((unsigned)f2bf(aHi[0]*sn) << 16));
    outv.y = (int)(((unsigned)f2bf(aLo[1]*sn)) | ((unsigned)f2bf(aHi[1]*sn) << 16));
    outv.z = (int)(((unsigned)f2bf(aLo[2]*sn)) | ((unsigned)f2bf(aHi[2]*sn) << 16));
    outv.w = (int)(((unsigned)f2bf(aLo[3]*sn)) | ((unsigned)f2bf(aHi[3]*sn) << 16));
    ((int4*)hpreb)[(size_t)npad*8 + fl] = outv;
  }
}

// K4: MFMA GCN GEMM + ReLU + mean pool + fused input projection.
// Also converts w_hh -> fp16 global (whh16) spread over 200 blocks, halving
// k_lstm's staging traffic.
__global__ __launch_bounds__(256) void k_gcn(
    const unsigned short* __restrict__ hpreb,
    const float* __restrict__ w_gcn,
    const float* __restrict__ b_gcn,
    const float* __restrict__ w_ih,
    const float* __restrict__ b_ih,
    const float* __restrict__ w_hh,
    int4* __restrict__ whh16,
    float* __restrict__ proj) {
  __shared__ unsigned short wLds[16*64*8];   // 16 KB
  __shared__ float pS[4*DG];
  __shared__ __align__(16) float hgS[DG];
  int t = threadIdx.x, g = blockIdx.x;
  // w_hh fp32 -> fp16 conversion slice (layout: i = k4*512 + r)
  for (int i = g*256 + t; i < 8192; i += N_GRAPHS*256) {
    int k4 = i >> 9, r = i & 511;
    const float4* wp = (const float4*)(w_hh + (size_t)r*HL + k4*8);
    float4 w0 = wp[0], w1 = wp[1];
    half2v p0 = {(_Float16)w0.x, (_Float16)w0.y};
    half2v p1 = {(_Float16)w0.z, (_Float16)w0.w};
    half2v p2 = {(_Float16)w1.x, (_Float16)w1.y};
    half2v p3 = {(_Float16)w1.z, (_Float16)w1.w};
    int4 pk;
    pk.x = __builtin_bit_cast(int, p0); pk.y = __builtin_bit_cast(int, p1);
    pk.z = __builtin_bit_cast(int, p2); pk.w = __builtin_bit_cast(int, p3);
    whh16[i] = pk;
  }
  for (int idx = t; idx < 16*64; idx += 256) {
    int f = idx >> 6, l = idx & 63;
    int h = f & 1, nt = f >> 1;
    int kbase = h*32 + (l >> 4)*8;
    int n = nt*16 + (l & 15);
    #pragma unroll
    for (int j = 0; j < 8; ++j)
      wLds[idx*8 + j] = f2bf(w_gcn[(kbase + j)*DG + n]);
  }
  __syncthreads();
  int w = t >> 6, lane = t & 63;
  int quad = lane >> 4, l15 = lane & 15;
  float bcol[8];
  #pragma unroll
  for (int nt = 0; nt < 8; ++nt) bcol[nt] = b_gcn[nt*16 + l15];
  float psum[8] = {0.f,0.f,0.f,0.f,0.f,0.f,0.f,0.f};
  const unsigned short* hb = hpreb + (size_t)g*NPGP*DIN;
  for (int i = 0; i < 8; ++i) {
    int rt = w + 4*i;
    int row0 = rt*16;
    const short8* aptr = (const short8*)(hb + (size_t)(row0 + l15)*DIN + quad*8);
    short8 a0 = aptr[0];
    short8 a1 = aptr[4];
    #pragma unroll
    for (int nt = 0; nt < 8; ++nt) {
      short8 b0 = *((const short8*)&wLds[((nt*2+0)*64 + lane)*8]);
      short8 b1 = *((const short8*)&wLds[((nt*2+1)*64 + lane)*8]);
      float4v acc = {0.f, 0.f, 0.f, 0.f};
      acc = __builtin_amdgcn_mfma_f32_16x16x32_bf16(a0, b0, acc, 0, 0, 0);
      acc = __builtin_amdgcn_mfma_f32_16x16x32_bf16(a1, b1, acc, 0, 0, 0);
      #pragma unroll
      for (int r = 0; r < 4; ++r) {
        int node = row0 + quad*4 + r;
        float v = acc[r] + bcol[nt];
        psum[nt] += (node < NPG) ? fmaxf(v, 0.f) : 0.f;
      }
    }
  }
  #pragma unroll
  for (int nt = 0; nt < 8; ++nt) {
    float v = psum[nt];
    v += __shfl_xor(v, 16);
    v += __shfl_xor(v, 32);
    if (lane < 16) pS[w*DG + nt*16 + lane] = v;
  }
  __syncthreads();
  if (t < DG)
    hgS[t] = (pS[t] + pS[DG+t] + pS[2*DG+t] + pS[3*DG+t]) * (1.0f/NPG);
  __syncthreads();
  for (int r = t; r < G4; r += 256) {
    const float4* wr = (const float4*)(w_ih + (size_t)r*HL);
    const float4* hv = (const float4*)hgS;
    float acc = b_ih[r];
    #pragma unroll
    for (int k4 = 0; k4 < 32; ++k4) {
      float4 w4 = wr[k4]; float4 h4 = hv[k4];
      acc += w4.x*h4.x + w4.y*h4.y + w4.z*h4.z + w4.w*h4.w;
    }
    proj[(size_t)g*G4 + r] = acc;
  }
}

// K5: LSTM — w_hh fp16 CU-resident in LDS (staged from pre-converted whh16);
// h packed fp16; fp32 accumulation via v_dot2_f32_f16; gates/c fp32.
__global__ __launch_bounds__(512) void k_lstm(const float* __restrict__ proj,
    const int4* __restrict__ whh16, const float* __restrict__ b_hh,
    const float* __restrict__ w_fc, const float* __restrict__ b_fc,
    float* __restrict__ out) {
  __shared__ int4 wL[16*512];        // 128 KB: [k4][r] = 8 fp16 of w_hh[r][k4*8..]
  __shared__ float gS[G4];
  __shared__ __align__(16) int4 hPi[16];  // 128 fp16 packed h state
  int b = blockIdx.x, t = threadIdx.x;
  for (int i = t; i < 16*512; i += 512) wL[i] = whh16[i];
  if (t < 16) hPi[t] = make_int4(0,0,0,0);
  float bh = b_hh[t];
  float c0 = 0.f, c1 = 0.f;
  __syncthreads();
  for (int l = 0; l < SEQ; ++l) {
    float acc = proj[(size_t)(b+l)*G4 + t] + bh;
    #pragma unroll
    for (int k4 = 0; k4 < 16; ++k4) {
      int4 wv = wL[(k4 << 9) + t];
      int4 hv = hPi[k4];
      acc = h2dot(__builtin_bit_cast(half2v, wv.x), __builtin_bit_cast(half2v, hv.x), acc);
      acc = h2dot(__builtin_bit_cast(half2v, wv.y), __builtin_bit_cast(half2v, hv.y), acc);
      acc = h2dot(__builtin_bit_cast(half2v, wv.z), __builtin_bit_cast(half2v, hv.z), acc);
      acc = h2dot(__builtin_bit_cast(half2v, wv.w), __builtin_bit_cast(half2v, hv.w), acc);
    }
    gS[t] = acc;
    __syncthreads();
    if (t < 64) {
      int j0 = 2*t, j1 = 2*t + 1;
      float i0 = sigmoidf_(gS[j0]),      i1 = sigmoidf_(gS[j1]);
      float f0 = sigmoidf_(gS[HL+j0]),   f1 = sigmoidf_(gS[HL+j1]);
      float g0 = tanhf(gS[2*HL+j0]),     g1 = tanhf(gS[2*HL+j1]);
      float o0 = sigmoidf_(gS[3*HL+j0]), o1 = sigmoidf_(gS[3*HL+j1]);
      c0 = f0*c0 + i0*g0;
      c1 = f1*c1 + i1*g1;
      float h0 = o0 * tanhf(c0);
      float h1 = o1 * tanhf(c1);
      half2v hp = {(_Float16)h0, (_Float16)h1};
      ((int*)hPi)[t] = __builtin_bit_cast(int, hp);
      if (l == SEQ-1) {
        float s = h0*w_fc[j0] + h1*w_fc[j1];
        #pragma unroll
        for (int off = 32; off > 0; off >>= 1) s += __shfl_down(s, off);
        if (t == 0) out[b] = s + b_fc[0];
      }
    }
    __syncthreads();
  }
}

extern "C" void kernel_launch(void* const* d_in, const int* in_sizes, int n_in,
                              void* d_out, int out_size, void* d_ws, size_t ws_size,
                              hipStream_t stream) {
  const float* x     = (const float*)d_in[0];
  const int*   src   = (const int*)d_in[1];
  const int*   dst   = (const int*)d_in[2];
  const float* w_gcn = (const float*)d_in[4];
  const float* b_gcn = (const float*)d_in[5];
  const float* w_ih  = (const float*)d_in[6];
  const float* w_hh  = (const float*)d_in[7];
  const float* b_ih  = (const float*)d_in[8];
  const float* b_hh  = (const float*)d_in[9];
  const float* w_fc  = (const float*)d_in[10];
  const float* b_fc  = (const float*)d_in[11];
  float* out = (float*)d_out;

  char* ws = (char*)d_ws;
  size_t off = 0;
  auto alloc = [&](size_t bytes) -> void* {
    void* p = ws + off; off += (bytes + 255) & ~(size_t)255; return p;
  };
  int* gcount  = (int*)alloc((size_t)N_GRAPHS*4);
  int* part    = (int*)alloc((size_t)N_GRAPHS*CAP*4);
  unsigned short* sorted_all = (unsigned short*)alloc((size_t)N_GRAPHS*CAP*2);
  int* e_end   = (int*)alloc((size_t)N_NODES_*4);
  int* e_deg   = (int*)alloc((size_t)N_NODES_*4);
  ushort4* xsb = (ushort4*)alloc((size_t)N_NODES_*DIN*2);
  unsigned short* hpreb = (unsigned short*)alloc((size_t)N_GRAPHS*NPGP*DIN*2);
  int4* whh16  = (int4*)alloc((size_t)8192*16);
  float* proj  = (float*)alloc((size_t)N_GRAPHS*G4*4);
  (void)ws_size; (void)in_sizes; (void)n_in; (void)out_size;

  hipMemsetAsync(gcount, 0, (size_t)N_GRAPHS*4, stream);
  k_part<<<NPART, 256, 0, stream>>>(src, dst, gcount, part);
  k_sort<<<N_GRAPHS, 512, 0, stream>>>(gcount, part, x, sorted_all, e_end, e_deg, xsb);
  k_agg<<<N_GRAPHS*4, 512, 0, stream>>>((const int4*)xsb, e_end, e_deg, sorted_all, hpreb);
  k_gcn<<<N_GRAPHS, 256, 0, stream>>>(hpreb, w_gcn, b_gcn, w_ih, b_ih, w_hh, whh16, proj);
  k_lstm<<<BWIN, 512, 0, stream>>>(proj, whh16, b_hh, w_fc, b_fc, out);
}